// Round 4
// baseline (402.139 us; speedup 1.0000x reference)
//
#include <hip/hip_runtime.h>

#define NB 256
#define ND 512
#define NC 80

// Module-scope device globals: no reliance on d_ws / ws_size.
// All distance-pipeline values stored in FP32 to mirror the numpy fp32 ref;
// accumulations in fp64 (≈ np pairwise-sum), rounded to fp32 at the same
// points the reference rounds.
__device__ float g_x [NB * ND];           // normalized rows (fp32), row-major
__device__ float g_xt[ND * NB];           // transposed copy (coalesced dot reads)
__device__ float g_sq[NB];                // fp32 sum of squares of normalized x
__device__ float g_d [NB * NB];           // fp32 euclidean distances
__device__ unsigned long long g_m[NB * 2];// label bitmasks (80 bits)
__device__ int g_atot[NB];                // per-anchor quadruplet totals

// cond = ((m1<=0.1)|(m2<=0.1)) & ((m1<=0)|(m2<=0))  ==  (m1<=0)|(m2<=0)
// and fl32(a-b)<=0  <=>  a<=b, so compare stored fp32 distances directly.
__device__ __forceinline__ bool accept_q(float din, float dij, float dik) {
    return (din <= dij) || (din <= dik);
}

__global__ __launch_bounds__(256) void k_norm(const float* __restrict__ logits) {
    int b = blockIdx.x, tid = threadIdx.x;
    __shared__ double red[NB];
    float v0 = logits[b * ND + tid];
    float v1 = logits[b * ND + 256 + tid];
    // square in fp32 (np does x*x elementwise in fp32), accumulate in fp64
    red[tid] = (double)(v0 * v0) + (double)(v1 * v1);
    __syncthreads();
    for (int off = 128; off > 0; off >>= 1) {
        if (tid < off) red[tid] += red[tid + off];
        __syncthreads();
    }
    float S = (float)red[0];          // round sum to fp32 (np sums in fp32)
    float nrm = sqrtf(S);             // fp32 sqrt
    __syncthreads();
    float a0 = v0 / nrm;              // fp32 divide, as np does
    float a1 = v1 / nrm;
    g_x[b * ND + tid]          = a0;
    g_x[b * ND + 256 + tid]    = a1;
    g_xt[tid * NB + b]         = a0;
    g_xt[(tid + 256) * NB + b] = a1;
    // sq = sum(xhat*xhat): fp32 squares, fp64 accumulate, round to fp32
    red[tid] = (double)(a0 * a0) + (double)(a1 * a1);
    __syncthreads();
    for (int off = 128; off > 0; off >>= 1) {
        if (tid < off) red[tid] += red[tid + off];
        __syncthreads();
    }
    if (tid == 0) g_sq[b] = (float)red[0];
}

__global__ __launch_bounds__(256) void k_masks(const float* __restrict__ labels) {
    int b = threadIdx.x;  // single block of 256
    unsigned long long m0 = 0, m1 = 0;
    for (int c = 0; c < 64; ++c)
        if (labels[b * NC + c] != 0.0f) m0 |= 1ULL << c;
    for (int c = 64; c < NC; ++c)
        if (labels[b * NC + c] != 0.0f) m1 |= 1ULL << (c - 64);
    g_m[2 * b] = m0;
    g_m[2 * b + 1] = m1;
}

__global__ __launch_bounds__(256) void k_dist() {
    int i = blockIdx.x, j = threadIdx.x;
    __shared__ float xi[ND];
    xi[j]       = g_x[i * ND + j];
    xi[j + 256] = g_x[i * ND + 256 + j];
    __syncthreads();
    double dot = 0.0;
    #pragma unroll 8
    for (int c = 0; c < ND; ++c)
        dot = fma((double)xi[c], (double)g_xt[c * NB + j], dot);
    float dotf = (float)dot;                   // round matmul result to fp32
    float t    = g_sq[i] + g_sq[j];            // fp32, np eval order
    float d2   = t - 2.0f * dotf;              // fp32
    g_d[i * NB + j] = sqrtf(d2 > 0.0f ? d2 : 0.0f);
}

__global__ __launch_bounds__(256) void k_count() {
    int i = blockIdx.x, tid = threadIdx.x;
    __shared__ float dd[NB];
    __shared__ int negf[NB];
    __shared__ short plist[NB];
    __shared__ int shP;
    __shared__ int red[NB];
    dd[tid] = g_d[i * NB + tid];
    if (tid == 0) {
        unsigned long long mi0 = g_m[2 * i], mi1 = g_m[2 * i + 1];
        int p = 0;
        for (int n = 0; n < NB; ++n) {
            bool shl = ((g_m[2 * n] & mi0) | (g_m[2 * n + 1] & mi1)) != 0ULL;
            negf[n] = shl ? 0 : 1;
            if (shl && n != i) plist[p++] = (short)n;
        }
        shP = p;
    }
    __syncthreads();
    int P = shP, T = P * (P - 1) / 2;
    int total = 0;
    for (int t = tid; t < T; t += NB) {
        int a = 0, base = 0;
        while (base + (P - 1 - a) <= t) { base += P - 1 - a; ++a; }
        int b = a + 1 + (t - base);
        float dij = dd[plist[a]], dik = dd[plist[b]];
        int c = 0;
        for (int n = 0; n < NB; ++n)
            if (negf[n] && accept_q(dd[n], dij, dik)) ++c;
        total += c;
    }
    red[tid] = total;
    __syncthreads();
    for (int off = 128; off > 0; off >>= 1) {
        if (tid < off) red[tid] += red[tid + off];
        __syncthreads();
    }
    if (tid == 0) g_atot[i] = red[0];
}

__global__ __launch_bounds__(256) void k_write(int4* __restrict__ out, int maxQuads) {
    int i = blockIdx.x, tid = threadIdx.x;
    __shared__ float dd[NB];
    __shared__ int negf[NB];
    __shared__ short plist[NB];
    __shared__ int shP, shBase, shChunk;
    __shared__ int scnt[NB], soff[NB];
    dd[tid] = g_d[i * NB + tid];
    if (tid == 0) {
        unsigned long long mi0 = g_m[2 * i], mi1 = g_m[2 * i + 1];
        int p = 0;
        for (int n = 0; n < NB; ++n) {
            bool shl = ((g_m[2 * n] & mi0) | (g_m[2 * n + 1] & mi1)) != 0ULL;
            negf[n] = shl ? 0 : 1;
            if (shl && n != i) plist[p++] = (short)n;
        }
        shP = p;
        int base = 0;
        for (int q = 0; q < i; ++q) base += g_atot[q];
        shBase = base;
    }
    __syncthreads();
    int P = shP, T = P * (P - 1) / 2;
    int anchorBase = shBase;
    int carried = 0;
    for (int cb = 0; cb < T; cb += NB) {
        int t = cb + tid;
        int myCnt = 0, jj = 0, kk = 0;
        float dij = 0.0f, dik = 0.0f;
        if (t < T) {
            int a = 0, base = 0;
            while (base + (P - 1 - a) <= t) { base += P - 1 - a; ++a; }
            int b = a + 1 + (t - base);
            jj = plist[a]; kk = plist[b];
            dij = dd[jj];  dik = dd[kk];
            for (int n = 0; n < NB; ++n)
                if (negf[n] && accept_q(dd[n], dij, dik)) ++myCnt;
        }
        scnt[tid] = myCnt;
        __syncthreads();
        if (tid == 0) {
            int s = 0;
            for (int q = 0; q < NB; ++q) { soff[q] = s; s += scnt[q]; }
            shChunk = s;
        }
        __syncthreads();
        if (myCnt > 0) {
            int w = anchorBase + carried + soff[tid];
            for (int n = 0; n < NB; ++n) {
                if (negf[n] && accept_q(dd[n], dij, dik)) {
                    if (w < maxQuads) out[w] = make_int4(i, jj, kk, n);
                    ++w;
                }
            }
        }
        carried += shChunk;
        __syncthreads();  // protect scnt/soff/shChunk before next chunk
    }
}

extern "C" void kernel_launch(void* const* d_in, const int* in_sizes, int n_in,
                              void* d_out, int out_size, void* d_ws, size_t ws_size,
                              hipStream_t stream) {
    const float* logits = (const float*)d_in[0];
    const float* labels = (const float*)d_in[1];
    // Defensive: if input order is swapped, detect via sizes.
    if (n_in >= 2 && in_sizes[0] == NB * NC && in_sizes[1] == NB * ND) {
        logits = (const float*)d_in[1];
        labels = (const float*)d_in[0];
    }
    int maxQuads = out_size / 4;

    k_norm <<<NB, NB, 0, stream>>>(logits);
    k_masks<<<1,  NB, 0, stream>>>(labels);
    k_dist <<<NB, NB, 0, stream>>>();
    k_count<<<NB, NB, 0, stream>>>();
    k_write<<<NB, NB, 0, stream>>>((int4*)d_out, maxQuads);
}

// Round 5
// 261.815 us; speedup vs baseline: 1.5360x; 1.5360x over previous
//
#include <hip/hip_runtime.h>
#include <math.h>

#define NB 256
#define ND 512
#define NC 80

// Module-scope device globals (no reliance on d_ws).
__device__ float g_x [NB * ND];           // normalized rows (fp32)
__device__ float g_xt[ND * NB];           // transposed copy
__device__ float g_sq[NB];                // fp32 sum of squares of normalized x
__device__ float g_d [NB * NB];           // fp32 euclidean distances
__device__ unsigned long long g_m[NB * 2];// label bitmasks (80 bits)
__device__ int g_atot[NB];                // per-anchor quadruplet totals

// Inclusive Hillis-Steele scan over 256 threads. tmp[255] = total after call.
// Leading barrier protects prior reads of tmp; trailing barriers make all
// LDS writes issued before the call visible after it.
__device__ __forceinline__ int block_scan(int val, int* tmp) {
    int tid = threadIdx.x;
    __syncthreads();
    tmp[tid] = val;
    __syncthreads();
    #pragma unroll
    for (int off = 1; off < 256; off <<= 1) {
        int v = (tid >= off) ? tmp[tid - off] : 0;
        __syncthreads();
        tmp[tid] += v;
        __syncthreads();
    }
    return tmp[tid];
}

// count = #{x in sorted[0..255] : x <= thr}; branchless bit-descent.
__device__ __forceinline__ int ubcount(const float* s, float thr) {
    int pos = 0;
    #pragma unroll
    for (int step = 128; step > 0; step >>= 1) {
        int np = pos + step;
        if (s[np - 1] <= thr) pos = np;
    }
    return pos;
}

__global__ __launch_bounds__(256) void k_norm(const float* __restrict__ logits) {
    int b = blockIdx.x, tid = threadIdx.x;
    __shared__ double red[NB];
    float v0 = logits[b * ND + tid];
    float v1 = logits[b * ND + 256 + tid];
    red[tid] = (double)(v0 * v0) + (double)(v1 * v1);
    __syncthreads();
    for (int off = 128; off > 0; off >>= 1) {
        if (tid < off) red[tid] += red[tid + off];
        __syncthreads();
    }
    float S = (float)red[0];
    float nrm = sqrtf(S);
    __syncthreads();
    float a0 = v0 / nrm;
    float a1 = v1 / nrm;
    g_x[b * ND + tid]          = a0;
    g_x[b * ND + 256 + tid]    = a1;
    g_xt[tid * NB + b]         = a0;
    g_xt[(tid + 256) * NB + b] = a1;
    red[tid] = (double)(a0 * a0) + (double)(a1 * a1);
    __syncthreads();
    for (int off = 128; off > 0; off >>= 1) {
        if (tid < off) red[tid] += red[tid + off];
        __syncthreads();
    }
    if (tid == 0) g_sq[b] = (float)red[0];
}

__global__ __launch_bounds__(256) void k_masks(const float* __restrict__ labels) {
    int b = threadIdx.x;
    unsigned long long m0 = 0, m1 = 0;
    for (int c = 0; c < 64; ++c)
        if (labels[b * NC + c] != 0.0f) m0 |= 1ULL << c;
    for (int c = 64; c < NC; ++c)
        if (labels[b * NC + c] != 0.0f) m1 |= 1ULL << (c - 64);
    g_m[2 * b] = m0;
    g_m[2 * b + 1] = m1;
}

__global__ __launch_bounds__(256) void k_dist() {
    int i = blockIdx.x, j = threadIdx.x;
    __shared__ float xi[ND];
    xi[j]       = g_x[i * ND + j];
    xi[j + 256] = g_x[i * ND + 256 + j];
    __syncthreads();
    double dot = 0.0;
    #pragma unroll 8
    for (int c = 0; c < ND; ++c)
        dot = fma((double)xi[c], (double)g_xt[c * NB + j], dot);
    float dotf = (float)dot;
    float t    = g_sq[i] + g_sq[j];
    float d2   = t - 2.0f * dotf;
    g_d[i * NB + j] = sqrtf(d2 > 0.0f ? d2 : 0.0f);
}

// Shared prelude (identical in k_count / k_write):
//  s_dd     : distances for anchor i
//  s_ddneg  : dd if negative else +INF   (write-phase predicate array)
//  s_sort   : ascending bitonic sort of s_ddneg (counting array)
//  s_plist  : positives ascending; P positives
//  s_rowbase: rowbase[a] = a*(P-1) - a(a-1)/2 (triangular decode)
#define PRELUDE() \
    int i = blockIdx.x, tid = threadIdx.x; \
    float dv = g_d[i * NB + tid]; \
    s_dd[tid] = dv; \
    unsigned long long mi0 = g_m[2 * i],   mi1 = g_m[2 * i + 1]; \
    unsigned long long mt0 = g_m[2 * tid], mt1 = g_m[2 * tid + 1]; \
    bool shl   = ((mi0 & mt0) | (mi1 & mt1)) != 0ULL; \
    bool isPos = shl && (tid != i); \
    s_ddneg[tid] = shl ? INFINITY : dv; \
    int incl = block_scan(isPos ? 1 : 0, s_tmp); \
    int P = s_tmp[255]; \
    if (isPos) s_plist[incl - 1] = (short)tid; \
    if (tid < P - 1) s_rowbase[tid] = tid * (P - 1) - (tid * (tid - 1)) / 2; \
    s_sort[tid] = s_ddneg[tid]; \
    __syncthreads(); \
    for (int k = 2; k <= 256; k <<= 1) \
        for (int j = k >> 1; j > 0; j >>= 1) { \
            int p = tid ^ j; \
            float mine = s_sort[tid], oth = s_sort[p]; \
            bool keepmin = (((tid & k) == 0) == (tid < p)); \
            float res = keepmin ? fminf(mine, oth) : fmaxf(mine, oth); \
            __syncthreads(); \
            s_sort[tid] = res; \
            __syncthreads(); \
        } \
    int T = P * (P - 1) / 2;

#define DECODE_AB() \
    int a = 0; \
    _Pragma("unroll") \
    for (int step = 128; step > 0; step >>= 1) { \
        int na = a + step; \
        if (na <= P - 2 && s_rowbase[na] <= t) a = na; \
    } \
    int b = a + 1 + (t - s_rowbase[a]);

__global__ __launch_bounds__(256) void k_count() {
    __shared__ float s_dd[NB], s_ddneg[NB], s_sort[NB];
    __shared__ int s_tmp[NB], s_rowbase[NB];
    __shared__ short s_plist[NB];
    PRELUDE();
    int total = 0;
    for (int t = tid; t < T; t += NB) {
        DECODE_AB();
        float thr = fmaxf(s_dd[s_plist[a]], s_dd[s_plist[b]]);
        total += ubcount(s_sort, thr);
    }
    block_scan(total, s_tmp);
    if (tid == 0) g_atot[i] = s_tmp[255];
}

__global__ __launch_bounds__(256) void k_write(int4* __restrict__ out, int maxQuads) {
    __shared__ float s_dd[NB], s_ddneg[NB], s_sort[NB], s_thr[NB];
    __shared__ int s_tmp[NB], s_rowbase[NB], s_jk[NB], s_woff[NB];
    __shared__ short s_plist[NB];
    PRELUDE();
    // anchor base: prefix over per-anchor totals
    block_scan(g_atot[tid], s_tmp);
    int anchorBase = (i == 0) ? 0 : s_tmp[i - 1];
    int wv = tid >> 6, ln = tid & 63;
    int carried = 0;
    for (int cb = 0; cb < T; cb += NB) {
        int t = cb + tid;
        int cnt = 0;
        if (t < T) {
            DECODE_AB();
            int jj = s_plist[a], kk = s_plist[b];
            float thr = fmaxf(s_dd[jj], s_dd[kk]);
            s_jk[tid]  = jj | (kk << 8);
            s_thr[tid] = thr;
            cnt = ubcount(s_sort, thr);
        }
        int incl2 = block_scan(cnt, s_tmp);   // leading barrier: phase-2 of prev chunk done reading
        int chunkTotal = s_tmp[255];
        s_woff[tid] = anchorBase + carried + (incl2 - cnt);
        __syncthreads();                      // publish s_woff (s_jk/s_thr covered by scan barriers)
        int chunkN = (T - cb < NB) ? (T - cb) : NB;
        for (int tt = wv; tt < chunkN; tt += 4) {
            int jk = s_jk[tt];
            float thr = s_thr[tt];
            int base = s_woff[tt];
            int jj = jk & 255, kk = jk >> 8;
            int cum = 0;
            #pragma unroll
            for (int r = 0; r < 4; ++r) {
                int n = (r << 6) | ln;
                bool flag = (s_ddneg[n] <= thr);
                unsigned long long mask = __ballot(flag);
                if (flag) {
                    int pos = base + cum + __popcll(mask & ((1ULL << ln) - 1ULL));
                    if (pos < maxQuads) out[pos] = make_int4(i, jj, kk, n);
                }
                cum += __popcll(mask);
            }
        }
        carried += chunkTotal;
        __syncthreads();                      // protect s_jk/s_thr/s_woff before next chunk
    }
}

extern "C" void kernel_launch(void* const* d_in, const int* in_sizes, int n_in,
                              void* d_out, int out_size, void* d_ws, size_t ws_size,
                              hipStream_t stream) {
    const float* logits = (const float*)d_in[0];
    const float* labels = (const float*)d_in[1];
    if (n_in >= 2 && in_sizes[0] == NB * NC && in_sizes[1] == NB * ND) {
        logits = (const float*)d_in[1];
        labels = (const float*)d_in[0];
    }
    int maxQuads = out_size / 4;

    k_norm <<<NB, NB, 0, stream>>>(logits);
    k_masks<<<1,  NB, 0, stream>>>(labels);
    k_dist <<<NB, NB, 0, stream>>>();
    k_count<<<NB, NB, 0, stream>>>();
    k_write<<<NB, NB, 0, stream>>>((int4*)d_out, maxQuads);
}

// Round 6
// 206.006 us; speedup vs baseline: 1.9521x; 1.2709x over previous
//
#include <hip/hip_runtime.h>
#include <math.h>

#define NB 256
#define ND 512
#define NC 80
#define NSPLIT 8   // sibling blocks per anchor in k_write

// Module-scope device globals (no reliance on d_ws).
__device__ float g_x [NB * ND];           // normalized rows (fp32)
__device__ float g_xt[ND * NB];           // transposed copy
__device__ float g_sq[NB];                // fp32 sum of squares of normalized x
__device__ float g_d [NB * NB];           // fp32 euclidean distances
__device__ unsigned long long g_m[NB * 2];// label bitmasks (80 bits)
__device__ int g_atot[NB];                // per-anchor quadruplet totals

// Inclusive Hillis-Steele scan over 256 threads. tmp[255] = total after call.
__device__ __forceinline__ int block_scan(int val, int* tmp) {
    int tid = threadIdx.x;
    __syncthreads();
    tmp[tid] = val;
    __syncthreads();
    #pragma unroll
    for (int off = 1; off < 256; off <<= 1) {
        int v = (tid >= off) ? tmp[tid - off] : 0;
        __syncthreads();
        tmp[tid] += v;
        __syncthreads();
    }
    return tmp[tid];
}

// count = #{x in sorted[0..255] : x <= thr}; branchless bit-descent.
__device__ __forceinline__ int ubcount(const float* s, float thr) {
    int pos = 0;
    #pragma unroll
    for (int step = 128; step > 0; step >>= 1) {
        int np = pos + step;
        if (s[np - 1] <= thr) pos = np;
    }
    return pos;
}

__global__ __launch_bounds__(256) void k_norm(const float* __restrict__ logits) {
    int b = blockIdx.x, tid = threadIdx.x;
    __shared__ double red[NB];
    float v0 = logits[b * ND + tid];
    float v1 = logits[b * ND + 256 + tid];
    red[tid] = (double)(v0 * v0) + (double)(v1 * v1);
    __syncthreads();
    for (int off = 128; off > 0; off >>= 1) {
        if (tid < off) red[tid] += red[tid + off];
        __syncthreads();
    }
    float S = (float)red[0];
    float nrm = sqrtf(S);
    __syncthreads();
    float a0 = v0 / nrm;
    float a1 = v1 / nrm;
    g_x[b * ND + tid]          = a0;
    g_x[b * ND + 256 + tid]    = a1;
    g_xt[tid * NB + b]         = a0;
    g_xt[(tid + 256) * NB + b] = a1;
    red[tid] = (double)(a0 * a0) + (double)(a1 * a1);
    __syncthreads();
    for (int off = 128; off > 0; off >>= 1) {
        if (tid < off) red[tid] += red[tid + off];
        __syncthreads();
    }
    if (tid == 0) g_sq[b] = (float)red[0];
}

__global__ __launch_bounds__(256) void k_masks(const float* __restrict__ labels) {
    int b = threadIdx.x;
    unsigned long long m0 = 0, m1 = 0;
    for (int c = 0; c < 64; ++c)
        if (labels[b * NC + c] != 0.0f) m0 |= 1ULL << c;
    for (int c = 64; c < NC; ++c)
        if (labels[b * NC + c] != 0.0f) m1 |= 1ULL << (c - 64);
    g_m[2 * b] = m0;
    g_m[2 * b + 1] = m1;
}

__global__ __launch_bounds__(256) void k_dist() {
    int i = blockIdx.x, j = threadIdx.x;
    __shared__ float xi[ND];
    xi[j]       = g_x[i * ND + j];
    xi[j + 256] = g_x[i * ND + 256 + j];
    __syncthreads();
    double dot = 0.0;
    #pragma unroll 8
    for (int c = 0; c < ND; ++c)
        dot = fma((double)xi[c], (double)g_xt[c * NB + j], dot);
    float dotf = (float)dot;
    float t    = g_sq[i] + g_sq[j];
    float d2   = t - 2.0f * dotf;
    g_d[i * NB + j] = sqrtf(d2 > 0.0f ? d2 : 0.0f);
}

// Shared prelude. Expects `int i` (anchor) and `int tid` already defined.
#define PRELUDE() \
    float dv = g_d[i * NB + tid]; \
    s_dd[tid] = dv; \
    unsigned long long mi0 = g_m[2 * i],   mi1 = g_m[2 * i + 1]; \
    unsigned long long mt0 = g_m[2 * tid], mt1 = g_m[2 * tid + 1]; \
    bool shl   = ((mi0 & mt0) | (mi1 & mt1)) != 0ULL; \
    bool isPos = shl && (tid != i); \
    s_ddneg[tid] = shl ? INFINITY : dv; \
    int incl = block_scan(isPos ? 1 : 0, s_tmp); \
    int P = s_tmp[255]; \
    if (isPos) s_plist[incl - 1] = (short)tid; \
    if (tid < P - 1) s_rowbase[tid] = tid * (P - 1) - (tid * (tid - 1)) / 2; \
    s_sort[tid] = s_ddneg[tid]; \
    __syncthreads(); \
    for (int k = 2; k <= 256; k <<= 1) \
        for (int j = k >> 1; j > 0; j >>= 1) { \
            int p = tid ^ j; \
            float mine = s_sort[tid], oth = s_sort[p]; \
            bool keepmin = (((tid & k) == 0) == (tid < p)); \
            float res = keepmin ? fminf(mine, oth) : fmaxf(mine, oth); \
            __syncthreads(); \
            s_sort[tid] = res; \
            __syncthreads(); \
        } \
    int T = P * (P - 1) / 2;

#define DECODE_AB() \
    int a = 0; \
    _Pragma("unroll") \
    for (int step = 128; step > 0; step >>= 1) { \
        int na = a + step; \
        if (na <= P - 2 && s_rowbase[na] <= t) a = na; \
    } \
    int b = a + 1 + (t - s_rowbase[a]);

__global__ __launch_bounds__(256) void k_count() {
    __shared__ float s_dd[NB], s_ddneg[NB], s_sort[NB];
    __shared__ int s_tmp[NB], s_rowbase[NB];
    __shared__ short s_plist[NB];
    int i = blockIdx.x, tid = threadIdx.x;
    PRELUDE();
    int total = 0;
    for (int t = tid; t < T; t += NB) {
        DECODE_AB();
        float thr = fmaxf(s_dd[s_plist[a]], s_dd[s_plist[b]]);
        total += ubcount(s_sort, thr);
    }
    block_scan(total, s_tmp);
    if (tid == 0) g_atot[i] = s_tmp[255];
}

__global__ __launch_bounds__(256) void k_write(int4* __restrict__ out, int maxQuads) {
    __shared__ float s_dd[NB], s_ddneg[NB], s_sort[NB], s_thr[NB];
    __shared__ int s_tmp[NB], s_rowbase[NB], s_jk[NB], s_woff[NB];
    __shared__ short s_plist[NB];
    int i = blockIdx.x / NSPLIT;          // siblings consecutive -> share L2 lines
    int split = blockIdx.x % NSPLIT;
    int tid = threadIdx.x;
    PRELUDE();
    // anchor base: prefix over per-anchor totals (redundant in every block)
    block_scan(g_atot[tid], s_tmp);
    int anchorBase = (i == 0) ? 0 : s_tmp[i - 1];
    int wv = tid >> 6, ln = tid & 63;
    // anchor-constant negative distances cached in registers (no LDS in hot loop)
    float vneg[4];
    #pragma unroll
    for (int r = 0; r < 4; ++r) vneg[r] = s_ddneg[(r << 6) | ln];
    int stripe0 = (split << 2) | wv;      // this wave's first triplet in each chunk
    int carried = 0;
    for (int cb = 0; cb < T; cb += NB) {
        int t = cb + tid;
        int cnt = 0;
        if (t < T) {
            DECODE_AB();
            int jj = s_plist[a], kk = s_plist[b];
            float thr = fmaxf(s_dd[jj], s_dd[kk]);
            s_jk[tid]  = jj | (kk << 8);
            s_thr[tid] = thr;
            cnt = ubcount(s_sort, thr);
        }
        int incl2 = block_scan(cnt, s_tmp);   // barriers also publish s_jk/s_thr
        int chunkTotal = s_tmp[255];
        s_woff[tid] = anchorBase + carried + (incl2 - cnt);
        __syncthreads();                      // publish s_woff
        int chunkN = (T - cb < NB) ? (T - cb) : NB;
        for (int tt = stripe0; tt < chunkN; tt += NSPLIT * 4) {
            int jk    = s_jk[tt];
            float thr = s_thr[tt];
            int base  = s_woff[tt];
            int jj = jk & 255, kk = jk >> 8;
            int cum = 0;
            #pragma unroll
            for (int r = 0; r < 4; ++r) {
                bool flag = (vneg[r] <= thr);
                unsigned long long mask = __ballot(flag);
                if (flag) {
                    int pos = base + cum + __popcll(mask & ((1ULL << ln) - 1ULL));
                    if (pos < maxQuads) out[pos] = make_int4(i, jj, kk, (r << 6) | ln);
                }
                cum += __popcll(mask);
            }
        }
        carried += chunkTotal;
        __syncthreads();                      // protect s_jk/s_thr/s_woff next chunk
    }
}

extern "C" void kernel_launch(void* const* d_in, const int* in_sizes, int n_in,
                              void* d_out, int out_size, void* d_ws, size_t ws_size,
                              hipStream_t stream) {
    const float* logits = (const float*)d_in[0];
    const float* labels = (const float*)d_in[1];
    if (n_in >= 2 && in_sizes[0] == NB * NC && in_sizes[1] == NB * ND) {
        logits = (const float*)d_in[1];
        labels = (const float*)d_in[0];
    }
    int maxQuads = out_size / 4;

    k_norm <<<NB, NB, 0, stream>>>(logits);
    k_masks<<<1,  NB, 0, stream>>>(labels);
    k_dist <<<NB, NB, 0, stream>>>();
    k_count<<<NB, NB, 0, stream>>>();
    k_write<<<NB * NSPLIT, NB, 0, stream>>>((int4*)d_out, maxQuads);
}

// Round 7
// 196.401 us; speedup vs baseline: 2.0475x; 1.0489x over previous
//
#include <hip/hip_runtime.h>
#include <math.h>

#define NB 256
#define ND 512
#define NC 80
#define NSPLIT 8                 // sibling blocks per anchor in k_write
#define SLOT 32640               // max triplets per anchor (P=256 worst case)

// Module-scope device globals (no reliance on d_ws).
__device__ float g_x [NB * ND];           // normalized rows (fp32)
__device__ float g_xt[ND * NB];           // transposed copy
__device__ float g_sq[NB];                // fp32 sum of squares of normalized x
__device__ float g_ddneg[NB * NB];        // dist if negative else +INF
__device__ unsigned long long g_m[NB * 2];// label bitmasks (80 bits)
__device__ int   g_atot[NB];              // per-anchor quadruplet totals
__device__ int   g_abase[NB];             // exclusive prefix of g_atot
__device__ int   g_T[NB];                 // per-anchor triplet count
__device__ int   g_jk [NB * SLOT];        // per-triplet packed (j | k<<8)
__device__ float g_thr[NB * SLOT];        // per-triplet threshold
__device__ int   g_cnt[NB * SLOT];        // per-triplet accepted-negative count

// Inclusive Hillis-Steele scan over 256 threads. tmp[255] = total after call.
__device__ __forceinline__ int block_scan(int val, int* tmp) {
    int tid = threadIdx.x;
    __syncthreads();
    tmp[tid] = val;
    __syncthreads();
    #pragma unroll
    for (int off = 1; off < 256; off <<= 1) {
        int v = (tid >= off) ? tmp[tid - off] : 0;
        __syncthreads();
        tmp[tid] += v;
        __syncthreads();
    }
    return tmp[tid];
}

// count = #{x in sorted[0..255] : x <= thr}; branchless bit-descent.
__device__ __forceinline__ int ubcount(const float* s, float thr) {
    int pos = 0;
    #pragma unroll
    for (int step = 128; step > 0; step >>= 1) {
        int np = pos + step;
        if (s[np - 1] <= thr) pos = np;
    }
    return pos;
}

// norm (byte-identical math to prior k_norm) + label masks fused
__global__ __launch_bounds__(256) void k_prep(const float* __restrict__ logits,
                                              const float* __restrict__ labels) {
    int b = blockIdx.x, tid = threadIdx.x;
    __shared__ double red[NB];
    float v0 = logits[b * ND + tid];
    float v1 = logits[b * ND + 256 + tid];
    red[tid] = (double)(v0 * v0) + (double)(v1 * v1);
    __syncthreads();
    for (int off = 128; off > 0; off >>= 1) {
        if (tid < off) red[tid] += red[tid + off];
        __syncthreads();
    }
    float S = (float)red[0];
    float nrm = sqrtf(S);
    __syncthreads();
    float a0 = v0 / nrm;
    float a1 = v1 / nrm;
    g_x[b * ND + tid]          = a0;
    g_x[b * ND + 256 + tid]    = a1;
    g_xt[tid * NB + b]         = a0;
    g_xt[(tid + 256) * NB + b] = a1;
    red[tid] = (double)(a0 * a0) + (double)(a1 * a1);
    __syncthreads();
    for (int off = 128; off > 0; off >>= 1) {
        if (tid < off) red[tid] += red[tid + off];
        __syncthreads();
    }
    if (tid == 0) g_sq[b] = (float)red[0];
    int wv = tid >> 6, ln = tid & 63;
    if (wv == 0) {
        unsigned long long m0 = __ballot(labels[b * NC + ln] != 0.0f);
        if (ln == 0) g_m[2 * b] = m0;
    } else if (wv == 1) {
        bool p = (ln < 16) ? (labels[b * NC + 64 + ln] != 0.0f) : false;
        unsigned long long m1 = __ballot(p);
        if (ln == 0) g_m[2 * b + 1] = m1;
    }
}

// distance row (byte-identical math to prior k_dist) + sort + per-triplet tables
__global__ __launch_bounds__(256) void k_count() {
    __shared__ float xi[ND];
    __shared__ float s_dd[NB], s_ddneg[NB], s_sort[NB];
    __shared__ int s_tmp[NB], s_rowbase[NB];
    __shared__ short s_plist[NB];
    int i = blockIdx.x, tid = threadIdx.x;
    xi[tid]       = g_x[i * ND + tid];
    xi[tid + 256] = g_x[i * ND + 256 + tid];
    __syncthreads();
    double dot = 0.0;
    #pragma unroll 8
    for (int c = 0; c < ND; ++c)
        dot = fma((double)xi[c], (double)g_xt[c * NB + tid], dot);
    float dotf = (float)dot;
    float sm   = g_sq[i] + g_sq[tid];
    float d2   = sm - 2.0f * dotf;
    float dv   = sqrtf(d2 > 0.0f ? d2 : 0.0f);
    s_dd[tid] = dv;
    unsigned long long mi0 = g_m[2 * i],   mi1 = g_m[2 * i + 1];
    unsigned long long mt0 = g_m[2 * tid], mt1 = g_m[2 * tid + 1];
    bool shl   = ((mi0 & mt0) | (mi1 & mt1)) != 0ULL;
    bool isPos = shl && (tid != i);
    float ddneg = shl ? INFINITY : dv;
    s_ddneg[tid] = ddneg;
    g_ddneg[i * NB + tid] = ddneg;
    int incl = block_scan(isPos ? 1 : 0, s_tmp);
    int P = s_tmp[255];
    if (isPos) s_plist[incl - 1] = (short)tid;
    if (tid < P - 1) s_rowbase[tid] = tid * (P - 1) - (tid * (tid - 1)) / 2;
    s_sort[tid] = s_ddneg[tid];
    __syncthreads();
    for (int k = 2; k <= 256; k <<= 1)
        for (int j = k >> 1; j > 0; j >>= 1) {
            int p = tid ^ j;
            float mine = s_sort[tid], oth = s_sort[p];
            bool keepmin = (((tid & k) == 0) == (tid < p));
            float res = keepmin ? fminf(mine, oth) : fmaxf(mine, oth);
            __syncthreads();
            s_sort[tid] = res;
            __syncthreads();
        }
    int T = P * (P - 1) / 2;
    if (tid == 0) g_T[i] = T;
    int total = 0;
    for (int t = tid; t < T; t += NB) {
        int a = 0;
        #pragma unroll
        for (int step = 128; step > 0; step >>= 1) {
            int na = a + step;
            if (na <= P - 2 && s_rowbase[na] <= t) a = na;
        }
        int b = a + 1 + (t - s_rowbase[a]);
        int jj = s_plist[a], kk = s_plist[b];
        float thr = fmaxf(s_dd[jj], s_dd[kk]);
        int c = ubcount(s_sort, thr);
        total += c;
        g_jk [i * SLOT + t] = jj | (kk << 8);
        g_thr[i * SLOT + t] = thr;
        g_cnt[i * SLOT + t] = c;
    }
    block_scan(total, s_tmp);
    if (tid == 0) g_atot[i] = s_tmp[255];
}

__global__ __launch_bounds__(256) void k_abase() {
    __shared__ int s_tmp[NB];
    int tid = threadIdx.x;
    int v = g_atot[tid];
    int incl = block_scan(v, s_tmp);
    g_abase[tid] = incl - v;     // exclusive prefix
}

__global__ __launch_bounds__(256) void k_write(int4* __restrict__ out, int maxQuads) {
    __shared__ int s_tmp[NB], s_jk[NB], s_woff[NB];
    __shared__ float s_thr[NB];
    int i = blockIdx.x / NSPLIT;
    int split = blockIdx.x % NSPLIT;
    int tid = threadIdx.x;
    int wv = tid >> 6, ln = tid & 63;
    float vneg[4];
    #pragma unroll
    for (int r = 0; r < 4; ++r) vneg[r] = g_ddneg[i * NB + ((r << 6) | ln)];
    int T = g_T[i];
    int anchorBase = g_abase[i];
    int stripe0 = (split << 2) | wv;
    int carried = 0;
    for (int cb = 0; cb < T; cb += NB) {
        int t = cb + tid;
        int cnt = 0;
        if (t < T) {
            cnt       = g_cnt[i * SLOT + t];
            s_jk[tid] = g_jk [i * SLOT + t];
            s_thr[tid]= g_thr[i * SLOT + t];
        }
        int incl = block_scan(cnt, s_tmp);   // barriers also publish s_jk/s_thr
        int chunkTotal = s_tmp[255];
        s_woff[tid] = anchorBase + carried + (incl - cnt);
        __syncthreads();                     // publish s_woff
        int chunkN = (T - cb < NB) ? (T - cb) : NB;
        for (int tt = stripe0; tt < chunkN; tt += NSPLIT * 4) {
            int jk    = s_jk[tt];
            float thr = s_thr[tt];
            int base  = s_woff[tt];
            int jj = jk & 255, kk = jk >> 8;
            int cum = 0;
            #pragma unroll
            for (int r = 0; r < 4; ++r) {
                bool flag = (vneg[r] <= thr);
                unsigned long long mask = __ballot(flag);
                if (flag) {
                    int pos = base + cum + __popcll(mask & ((1ULL << ln) - 1ULL));
                    if (pos < maxQuads) out[pos] = make_int4(i, jj, kk, (r << 6) | ln);
                }
                cum += __popcll(mask);
            }
        }
        carried += chunkTotal;
        __syncthreads();                     // protect s_jk/s_thr/s_woff next chunk
    }
}

extern "C" void kernel_launch(void* const* d_in, const int* in_sizes, int n_in,
                              void* d_out, int out_size, void* d_ws, size_t ws_size,
                              hipStream_t stream) {
    const float* logits = (const float*)d_in[0];
    const float* labels = (const float*)d_in[1];
    if (n_in >= 2 && in_sizes[0] == NB * NC && in_sizes[1] == NB * ND) {
        logits = (const float*)d_in[1];
        labels = (const float*)d_in[0];
    }
    int maxQuads = out_size / 4;

    k_prep <<<NB, NB, 0, stream>>>(logits, labels);
    k_count<<<NB, NB, 0, stream>>>();
    k_abase<<<1,  NB, 0, stream>>>();
    k_write<<<NB * NSPLIT, NB, 0, stream>>>((int4*)d_out, maxQuads);
}

// Round 8
// 196.057 us; speedup vs baseline: 2.0511x; 1.0018x over previous
//
#include <hip/hip_runtime.h>
#include <math.h>

#define NB 256
#define ND 512
#define NC 80
#define NSPLIT 8                 // sibling blocks per anchor in k_write
#define SLOT 32640               // max triplets per anchor (P=256 worst case)

// Module-scope device globals (no reliance on d_ws).
__device__ float g_x [NB * ND];           // normalized rows (fp32)
__device__ float g_xt[ND * NB];           // transposed copy
__device__ float g_sq[NB];                // fp32 sum of squares of normalized x
__device__ float g_ddneg[NB * NB];        // dist if negative else +INF
__device__ unsigned long long g_m[NB * 2];// label bitmasks (80 bits)
__device__ int   g_atot[NB];              // per-anchor quadruplet totals
__device__ int   g_T[NB];                 // per-anchor triplet count
__device__ int4  g_trip[NB * SLOT];       // per-triplet {j|k<<8, thr bits, toff, -}

// Inclusive Hillis-Steele scan over 256 threads. tmp[255] = total after call.
__device__ __forceinline__ int block_scan(int val, int* tmp) {
    int tid = threadIdx.x;
    __syncthreads();
    tmp[tid] = val;
    __syncthreads();
    #pragma unroll
    for (int off = 1; off < 256; off <<= 1) {
        int v = (tid >= off) ? tmp[tid - off] : 0;
        __syncthreads();
        tmp[tid] += v;
        __syncthreads();
    }
    return tmp[tid];
}

// count = #{x in sorted[0..255] : x <= thr}; branchless bit-descent.
__device__ __forceinline__ int ubcount(const float* s, float thr) {
    int pos = 0;
    #pragma unroll
    for (int step = 128; step > 0; step >>= 1) {
        int np = pos + step;
        if (s[np - 1] <= thr) pos = np;
    }
    return pos;
}

// norm (byte-identical math to prior rounds) + label masks fused
__global__ __launch_bounds__(256) void k_prep(const float* __restrict__ logits,
                                              const float* __restrict__ labels) {
    int b = blockIdx.x, tid = threadIdx.x;
    __shared__ double red[NB];
    float v0 = logits[b * ND + tid];
    float v1 = logits[b * ND + 256 + tid];
    red[tid] = (double)(v0 * v0) + (double)(v1 * v1);
    __syncthreads();
    for (int off = 128; off > 0; off >>= 1) {
        if (tid < off) red[tid] += red[tid + off];
        __syncthreads();
    }
    float S = (float)red[0];
    float nrm = sqrtf(S);
    __syncthreads();
    float a0 = v0 / nrm;
    float a1 = v1 / nrm;
    g_x[b * ND + tid]          = a0;
    g_x[b * ND + 256 + tid]    = a1;
    g_xt[tid * NB + b]         = a0;
    g_xt[(tid + 256) * NB + b] = a1;
    red[tid] = (double)(a0 * a0) + (double)(a1 * a1);
    __syncthreads();
    for (int off = 128; off > 0; off >>= 1) {
        if (tid < off) red[tid] += red[tid + off];
        __syncthreads();
    }
    if (tid == 0) g_sq[b] = (float)red[0];
    int wv = tid >> 6, ln = tid & 63;
    if (wv == 0) {
        unsigned long long m0 = __ballot(labels[b * NC + ln] != 0.0f);
        if (ln == 0) g_m[2 * b] = m0;
    } else if (wv == 1) {
        bool p = (ln < 16) ? (labels[b * NC + 64 + ln] != 0.0f) : false;
        unsigned long long m1 = __ballot(p);
        if (ln == 0) g_m[2 * b + 1] = m1;
    }
}

// distance row (byte-identical math) + sort + per-triplet {jk,thr,toff} tables
__global__ __launch_bounds__(256) void k_count() {
    __shared__ float xi[ND];
    __shared__ float s_dd[NB], s_ddneg[NB], s_sort[NB];
    __shared__ int s_tmp[NB], s_rowbase[NB];
    __shared__ short s_plist[NB];
    int i = blockIdx.x, tid = threadIdx.x;
    xi[tid]       = g_x[i * ND + tid];
    xi[tid + 256] = g_x[i * ND + 256 + tid];
    __syncthreads();
    double dot = 0.0;
    #pragma unroll 8
    for (int c = 0; c < ND; ++c)
        dot = fma((double)xi[c], (double)g_xt[c * NB + tid], dot);
    float dotf = (float)dot;
    float sm   = g_sq[i] + g_sq[tid];
    float d2   = sm - 2.0f * dotf;
    float dv   = sqrtf(d2 > 0.0f ? d2 : 0.0f);
    s_dd[tid] = dv;
    unsigned long long mi0 = g_m[2 * i],   mi1 = g_m[2 * i + 1];
    unsigned long long mt0 = g_m[2 * tid], mt1 = g_m[2 * tid + 1];
    bool shl   = ((mi0 & mt0) | (mi1 & mt1)) != 0ULL;
    bool isPos = shl && (tid != i);
    float ddneg = shl ? INFINITY : dv;
    s_ddneg[tid] = ddneg;
    g_ddneg[i * NB + tid] = ddneg;
    int incl = block_scan(isPos ? 1 : 0, s_tmp);
    int P = s_tmp[255];
    if (isPos) s_plist[incl - 1] = (short)tid;
    if (tid < P - 1) s_rowbase[tid] = tid * (P - 1) - (tid * (tid - 1)) / 2;
    s_sort[tid] = s_ddneg[tid];
    __syncthreads();
    for (int k = 2; k <= 256; k <<= 1)
        for (int j = k >> 1; j > 0; j >>= 1) {
            int p = tid ^ j;
            float mine = s_sort[tid], oth = s_sort[p];
            bool keepmin = (((tid & k) == 0) == (tid < p));
            float res = keepmin ? fminf(mine, oth) : fmaxf(mine, oth);
            __syncthreads();
            s_sort[tid] = res;
            __syncthreads();
        }
    int T = P * (P - 1) / 2;
    if (tid == 0) g_T[i] = T;
    int carried = 0;
    for (int cb = 0; cb < T; cb += NB) {
        int t = cb + tid;
        int cnt = 0, jk = 0;
        float thr = 0.0f;
        if (t < T) {
            int a = 0;
            #pragma unroll
            for (int step = 128; step > 0; step >>= 1) {
                int na = a + step;
                if (na <= P - 2 && s_rowbase[na] <= t) a = na;
            }
            int b = a + 1 + (t - s_rowbase[a]);
            int jj = s_plist[a], kk = s_plist[b];
            thr = fmaxf(s_dd[jj], s_dd[kk]);
            jk  = jj | (kk << 8);
            cnt = ubcount(s_sort, thr);
        }
        int inc2 = block_scan(cnt, s_tmp);
        if (t < T)
            g_trip[i * SLOT + t] =
                make_int4(jk, __float_as_int(thr), carried + inc2 - cnt, 0);
        carried += s_tmp[255];
    }
    if (tid == 0) g_atot[i] = carried;
}

// barrier-free emission: one int4 broadcast load per triplet, ballot-compacted
// coalesced stores. 32 waves per anchor (8 blocks x 4 waves), stripe t%32.
__global__ __launch_bounds__(256) void k_write(int4* __restrict__ out, int maxQuads) {
    __shared__ int s_tmp[NB];
    int i = blockIdx.x / NSPLIT;
    int split = blockIdx.x % NSPLIT;
    int tid = threadIdx.x;
    int wv = tid >> 6, ln = tid & 63;
    // anchor base: redundant per-block scan of per-anchor totals (~10 barriers)
    block_scan(g_atot[tid], s_tmp);
    int anchorBase = s_tmp[i] - g_atot[i];
    float vneg[4];
    #pragma unroll
    for (int r = 0; r < 4; ++r) vneg[r] = g_ddneg[i * NB + ((r << 6) | ln)];
    int T = g_T[i];
    int waveId = (split << 2) | wv;           // 0..31
    for (int t = waveId; t < T; t += NSPLIT * 4) {
        int4 tr = g_trip[i * SLOT + t];       // wave-uniform broadcast load
        int jj = tr.x & 255, kk = tr.x >> 8;
        float thr = __int_as_float(tr.y);
        int base = anchorBase + tr.z;
        int cum = 0;
        #pragma unroll
        for (int r = 0; r < 4; ++r) {
            bool flag = (vneg[r] <= thr);
            unsigned long long mask = __ballot(flag);
            if (flag) {
                int pos = base + cum + __popcll(mask & ((1ULL << ln) - 1ULL));
                if (pos < maxQuads) out[pos] = make_int4(i, jj, kk, (r << 6) | ln);
            }
            cum += __popcll(mask);
        }
    }
}

extern "C" void kernel_launch(void* const* d_in, const int* in_sizes, int n_in,
                              void* d_out, int out_size, void* d_ws, size_t ws_size,
                              hipStream_t stream) {
    const float* logits = (const float*)d_in[0];
    const float* labels = (const float*)d_in[1];
    if (n_in >= 2 && in_sizes[0] == NB * NC && in_sizes[1] == NB * ND) {
        logits = (const float*)d_in[1];
        labels = (const float*)d_in[0];
    }
    int maxQuads = out_size / 4;

    k_prep <<<NB, NB, 0, stream>>>(logits, labels);
    k_count<<<NB, NB, 0, stream>>>();
    k_write<<<NB * NSPLIT, NB, 0, stream>>>((int4*)d_out, maxQuads);
}

// Round 9
// 191.705 us; speedup vs baseline: 2.0977x; 1.0227x over previous
//
#include <hip/hip_runtime.h>
#include <math.h>

#define NB 256
#define ND 512
#define NC 80
#define NSPLIT 8                 // sibling blocks per anchor in k_write
#define SLOT 32640               // max triplets per anchor (P=256 worst case)

// Module-scope device globals (no reliance on d_ws).
__device__ float g_x [NB * ND];           // normalized rows (fp32)
__device__ float g_xt[ND * NB];           // transposed copy
__device__ float g_sq[NB];                // fp32 sum of squares of normalized x
__device__ float g_ddneg[NB * NB];        // dist if negative else +INF
__device__ unsigned long long g_m[NB * 2];// label bitmasks (80 bits)
__device__ int   g_atot[NB];              // per-anchor quadruplet totals
__device__ int   g_T[NB];                 // per-anchor triplet count
__device__ int4  g_trip[NB * SLOT];       // per-triplet {j|k<<8, thr bits, toff, -}

// Inclusive Hillis-Steele scan over 256 threads. tmp[255] = total after call.
__device__ __forceinline__ int block_scan(int val, int* tmp) {
    int tid = threadIdx.x;
    __syncthreads();
    tmp[tid] = val;
    __syncthreads();
    #pragma unroll
    for (int off = 1; off < 256; off <<= 1) {
        int v = (tid >= off) ? tmp[tid - off] : 0;
        __syncthreads();
        tmp[tid] += v;
        __syncthreads();
    }
    return tmp[tid];
}

// count = #{x in sorted[0..255] : x <= thr}; branchless bit-descent.
__device__ __forceinline__ int ubcount(const float* s, float thr) {
    int pos = 0;
    #pragma unroll
    for (int step = 128; step > 0; step >>= 1) {
        int np = pos + step;
        if (s[np - 1] <= thr) pos = np;
    }
    return pos;
}

// norm (byte-identical math to prior rounds) + label masks fused
__global__ __launch_bounds__(256) void k_prep(const float* __restrict__ logits,
                                              const float* __restrict__ labels) {
    int b = blockIdx.x, tid = threadIdx.x;
    __shared__ double red[NB];
    float v0 = logits[b * ND + tid];
    float v1 = logits[b * ND + 256 + tid];
    red[tid] = (double)(v0 * v0) + (double)(v1 * v1);
    __syncthreads();
    for (int off = 128; off > 0; off >>= 1) {
        if (tid < off) red[tid] += red[tid + off];
        __syncthreads();
    }
    float S = (float)red[0];
    float nrm = sqrtf(S);
    __syncthreads();
    float a0 = v0 / nrm;
    float a1 = v1 / nrm;
    g_x[b * ND + tid]          = a0;
    g_x[b * ND + 256 + tid]    = a1;
    g_xt[tid * NB + b]         = a0;
    g_xt[(tid + 256) * NB + b] = a1;
    red[tid] = (double)(a0 * a0) + (double)(a1 * a1);
    __syncthreads();
    for (int off = 128; off > 0; off >>= 1) {
        if (tid < off) red[tid] += red[tid + off];
        __syncthreads();
    }
    if (tid == 0) g_sq[b] = (float)red[0];
    int wv = tid >> 6, ln = tid & 63;
    if (wv == 0) {
        unsigned long long m0 = __ballot(labels[b * NC + ln] != 0.0f);
        if (ln == 0) g_m[2 * b] = m0;
    } else if (wv == 1) {
        bool p = (ln < 16) ? (labels[b * NC + 64 + ln] != 0.0f) : false;
        unsigned long long m1 = __ballot(p);
        if (ln == 0) g_m[2 * b + 1] = m1;
    }
}

// distance row (byte-identical math) + hybrid bitonic sort + per-triplet tables
__global__ __launch_bounds__(256) void k_count() {
    __shared__ float xi[ND];
    __shared__ float s_dd[NB], s_ddneg[NB], s_sort[NB];
    __shared__ int s_tmp[NB], s_rowbase[NB];
    __shared__ short s_plist[NB];
    int i = blockIdx.x, tid = threadIdx.x;
    xi[tid]       = g_x[i * ND + tid];
    xi[tid + 256] = g_x[i * ND + 256 + tid];
    __syncthreads();
    double dot = 0.0;
    #pragma unroll 8
    for (int c = 0; c < ND; ++c)
        dot = fma((double)xi[c], (double)g_xt[c * NB + tid], dot);
    float dotf = (float)dot;
    float sm   = g_sq[i] + g_sq[tid];
    float d2   = sm - 2.0f * dotf;
    float dv   = sqrtf(d2 > 0.0f ? d2 : 0.0f);
    s_dd[tid] = dv;
    unsigned long long mi0 = g_m[2 * i],   mi1 = g_m[2 * i + 1];
    unsigned long long mt0 = g_m[2 * tid], mt1 = g_m[2 * tid + 1];
    bool shl   = ((mi0 & mt0) | (mi1 & mt1)) != 0ULL;
    bool isPos = shl && (tid != i);
    float ddneg = shl ? INFINITY : dv;
    s_ddneg[tid] = ddneg;
    g_ddneg[i * NB + tid] = ddneg;
    int incl = block_scan(isPos ? 1 : 0, s_tmp);
    int P = s_tmp[255];
    if (isPos) s_plist[incl - 1] = (short)tid;
    if (tid < P - 1) s_rowbase[tid] = tid * (P - 1) - (tid * (tid - 1)) / 2;
    // Hybrid bitonic: identical pairings/ops to the LDS version; stages with
    // j<=32 exchange within a wave via shfl_xor (tid<p  <=>  (tid&j)==0).
    float v = ddneg;
    for (int k = 2; k <= 256; k <<= 1)
        for (int j = k >> 1; j > 0; j >>= 1) {
            float oth;
            if (j >= 64) {
                __syncthreads();
                s_sort[tid] = v;
                __syncthreads();
                oth = s_sort[tid ^ j];
            } else {
                oth = __shfl_xor(v, j);
            }
            bool keepmin = (((tid & k) == 0) == ((tid & j) == 0));
            v = keepmin ? fminf(v, oth) : fmaxf(v, oth);
        }
    __syncthreads();
    s_sort[tid] = v;
    __syncthreads();
    int T = P * (P - 1) / 2;
    if (tid == 0) g_T[i] = T;
    int carried = 0;
    for (int cb = 0; cb < T; cb += NB) {
        int t = cb + tid;
        int cnt = 0, jk = 0;
        float thr = 0.0f;
        if (t < T) {
            int a = 0;
            #pragma unroll
            for (int step = 128; step > 0; step >>= 1) {
                int na = a + step;
                if (na <= P - 2 && s_rowbase[na] <= t) a = na;
            }
            int b = a + 1 + (t - s_rowbase[a]);
            int jj = s_plist[a], kk = s_plist[b];
            thr = fmaxf(s_dd[jj], s_dd[kk]);
            jk  = jj | (kk << 8);
            cnt = ubcount(s_sort, thr);
        }
        int inc2 = block_scan(cnt, s_tmp);
        if (t < T)
            g_trip[i * SLOT + t] =
                make_int4(jk, __float_as_int(thr), carried + inc2 - cnt, 0);
        carried += s_tmp[255];
    }
    if (tid == 0) g_atot[i] = carried;
}

// barrier-free emission, software-pipelined triplet loop.
__global__ __launch_bounds__(256) void k_write(int4* __restrict__ out, int maxQuads) {
    int i = blockIdx.x / NSPLIT;
    int split = blockIdx.x % NSPLIT;
    int tid = threadIdx.x;
    int wv = tid >> 6, ln = tid & 63;
    // anchorBase = sum_{m<i} g_atot[m] via per-wave shuffle reduce (no barriers)
    int psum = 0;
    for (int m = ln; m < i; m += 64) psum += g_atot[m];
    #pragma unroll
    for (int off = 1; off < 64; off <<= 1) psum += __shfl_xor(psum, off);
    int anchorBase = psum;   // identical in all lanes
    float vneg[4];
    #pragma unroll
    for (int r = 0; r < 4; ++r) vneg[r] = g_ddneg[i * NB + ((r << 6) | ln)];
    unsigned long long lanemask = (1ULL << ln) - 1ULL;
    int T = g_T[i];
    int waveId = (split << 2) | wv;           // 0..31
    int t = waveId;
    int4 tr = (t < T) ? g_trip[i * SLOT + t] : make_int4(0, 0, 0, 0);
    while (t < T) {
        int tn = t + NSPLIT * 4;
        int4 nxt = (tn < T) ? g_trip[i * SLOT + tn] : make_int4(0, 0, 0, 0);
        int jj = tr.x & 255, kk = tr.x >> 8;
        float thr = __int_as_float(tr.y);
        int base = anchorBase + tr.z;
        // all 4 compare/ballots up front (independent), then stores
        bool f0 = (vneg[0] <= thr), f1 = (vneg[1] <= thr);
        bool f2 = (vneg[2] <= thr), f3 = (vneg[3] <= thr);
        unsigned long long m0 = __ballot(f0), m1 = __ballot(f1);
        unsigned long long m2 = __ballot(f2), m3 = __ballot(f3);
        int b1 = base + __popcll(m0);
        int b2 = b1 + __popcll(m1);
        int b3 = b2 + __popcll(m2);
        if (f0) { int pos = base + __popcll(m0 & lanemask);
                  if (pos < maxQuads) out[pos] = make_int4(i, jj, kk, ln); }
        if (f1) { int pos = b1 + __popcll(m1 & lanemask);
                  if (pos < maxQuads) out[pos] = make_int4(i, jj, kk, 64 | ln); }
        if (f2) { int pos = b2 + __popcll(m2 & lanemask);
                  if (pos < maxQuads) out[pos] = make_int4(i, jj, kk, 128 | ln); }
        if (f3) { int pos = b3 + __popcll(m3 & lanemask);
                  if (pos < maxQuads) out[pos] = make_int4(i, jj, kk, 192 | ln); }
        tr = nxt;
        t = tn;
    }
}

extern "C" void kernel_launch(void* const* d_in, const int* in_sizes, int n_in,
                              void* d_out, int out_size, void* d_ws, size_t ws_size,
                              hipStream_t stream) {
    const float* logits = (const float*)d_in[0];
    const float* labels = (const float*)d_in[1];
    if (n_in >= 2 && in_sizes[0] == NB * NC && in_sizes[1] == NB * ND) {
        logits = (const float*)d_in[1];
        labels = (const float*)d_in[0];
    }
    int maxQuads = out_size / 4;

    k_prep <<<NB, NB, 0, stream>>>(logits, labels);
    k_count<<<NB, NB, 0, stream>>>();
    k_write<<<NB * NSPLIT, NB, 0, stream>>>((int4*)d_out, maxQuads);
}

// Round 10
// 187.564 us; speedup vs baseline: 2.1440x; 1.0221x over previous
//
#include <hip/hip_runtime.h>
#include <math.h>

#define NB 256
#define ND 512
#define NC 80
#define NSPLIT 8                 // blocks per anchor-equivalent in k_write grid
#define SLOT 32640               // max triplets per anchor (P=256 worst case)
#define KW_WAVES (NB * NSPLIT * 4)   // 8192 waves in k_write

// Module-scope device globals (no reliance on d_ws).
__device__ float g_x [NB * ND];           // normalized rows (fp32)
__device__ float g_xt[ND * NB];           // transposed copy
__device__ float g_sq[NB];                // fp32 sum of squares of normalized x
__device__ float g_ddneg[NB * NB];        // dist if negative else +INF
__device__ unsigned long long g_m[NB * 2];// label bitmasks (80 bits)
__device__ int   g_atot[NB];              // per-anchor quadruplet totals
__device__ int   g_abase[NB];             // exclusive prefix of g_atot
__device__ int   g_cursor;                // dense triplet-list cursor
__device__ int4  g_trip[NB * SLOT];       // dense {j|k<<8, thr bits, toff, anchor}

// Integer inclusive scan over 256 threads: wave shfl-scan + 2-barrier combine.
// After call, wsum[0..3] hold per-wave totals (total = sum of the 4).
__device__ __forceinline__ int block_scan_int(int val, int* wsum) {
    int tid = threadIdx.x, wv = tid >> 6, ln = tid & 63;
    int v = val;
    #pragma unroll
    for (int off = 1; off < 64; off <<= 1) {
        int u = __shfl_up(v, off);
        v += (ln >= off) ? u : 0;
    }
    __syncthreads();                 // protect prior wsum readers
    if (ln == 63) wsum[wv] = v;
    __syncthreads();
    int add = 0;
    #pragma unroll
    for (int w = 0; w < 4; ++w) if (w < wv) add += wsum[w];
    return v + add;
}

// count = #{x in sorted[0..255] : x <= thr}; branchless bit-descent.
__device__ __forceinline__ int ubcount(const float* s, float thr) {
    int pos = 0;
    #pragma unroll
    for (int step = 128; step > 0; step >>= 1) {
        int np = pos + step;
        if (s[np - 1] <= thr) pos = np;
    }
    return pos;
}

// norm (byte-identical fp64 tree to prior rounds) + label masks + cursor reset
__global__ __launch_bounds__(256) void k_prep(const float* __restrict__ logits,
                                              const float* __restrict__ labels) {
    int b = blockIdx.x, tid = threadIdx.x;
    __shared__ double red[NB];
    if (b == 0 && tid == 0) g_cursor = 0;
    float v0 = logits[b * ND + tid];
    float v1 = logits[b * ND + 256 + tid];
    red[tid] = (double)(v0 * v0) + (double)(v1 * v1);
    __syncthreads();
    for (int off = 128; off > 0; off >>= 1) {
        if (tid < off) red[tid] += red[tid + off];
        __syncthreads();
    }
    float S = (float)red[0];
    float nrm = sqrtf(S);
    __syncthreads();
    float a0 = v0 / nrm;
    float a1 = v1 / nrm;
    g_x[b * ND + tid]          = a0;
    g_x[b * ND + 256 + tid]    = a1;
    g_xt[tid * NB + b]         = a0;
    g_xt[(tid + 256) * NB + b] = a1;
    red[tid] = (double)(a0 * a0) + (double)(a1 * a1);
    __syncthreads();
    for (int off = 128; off > 0; off >>= 1) {
        if (tid < off) red[tid] += red[tid + off];
        __syncthreads();
    }
    if (tid == 0) g_sq[b] = (float)red[0];
    int wv = tid >> 6, ln = tid & 63;
    if (wv == 0) {
        unsigned long long m0 = __ballot(labels[b * NC + ln] != 0.0f);
        if (ln == 0) g_m[2 * b] = m0;
    } else if (wv == 1) {
        bool p = (ln < 16) ? (labels[b * NC + 64 + ln] != 0.0f) : false;
        unsigned long long m1 = __ballot(p);
        if (ln == 0) g_m[2 * b + 1] = m1;
    }
}

// distance row (byte-identical fp64 math) + hybrid bitonic sort + dense tables
__global__ __launch_bounds__(256) void k_count() {
    __shared__ float xi[ND];
    __shared__ float s_dd[NB], s_sort[NB];
    __shared__ int s_w4[4], s_rowbase[NB], s_base;
    __shared__ short s_plist[NB];
    int i = blockIdx.x, tid = threadIdx.x;
    xi[tid]       = g_x[i * ND + tid];
    xi[tid + 256] = g_x[i * ND + 256 + tid];
    __syncthreads();
    double dot = 0.0;
    #pragma unroll 8
    for (int c = 0; c < ND; ++c)
        dot = fma((double)xi[c], (double)g_xt[c * NB + tid], dot);
    float dotf = (float)dot;
    float sm   = g_sq[i] + g_sq[tid];
    float d2   = sm - 2.0f * dotf;
    float dv   = sqrtf(d2 > 0.0f ? d2 : 0.0f);
    s_dd[tid] = dv;
    unsigned long long mi0 = g_m[2 * i],   mi1 = g_m[2 * i + 1];
    unsigned long long mt0 = g_m[2 * tid], mt1 = g_m[2 * tid + 1];
    bool shl   = ((mi0 & mt0) | (mi1 & mt1)) != 0ULL;
    bool isPos = shl && (tid != i);
    float ddneg = shl ? INFINITY : dv;
    g_ddneg[i * NB + tid] = ddneg;
    int incl = block_scan_int(isPos ? 1 : 0, s_w4);
    int P = s_w4[0] + s_w4[1] + s_w4[2] + s_w4[3];
    if (isPos) s_plist[incl - 1] = (short)tid;
    if (tid < P - 1) s_rowbase[tid] = tid * (P - 1) - (tid * (tid - 1)) / 2;
    // Hybrid bitonic (identical pairings/ops to R9): j<=32 via shfl_xor.
    float v = ddneg;
    for (int k = 2; k <= 256; k <<= 1)
        for (int j = k >> 1; j > 0; j >>= 1) {
            float oth;
            if (j >= 64) {
                __syncthreads();
                s_sort[tid] = v;
                __syncthreads();
                oth = s_sort[tid ^ j];
            } else {
                oth = __shfl_xor(v, j);
            }
            bool keepmin = (((tid & k) == 0) == ((tid & j) == 0));
            v = keepmin ? fminf(v, oth) : fmaxf(v, oth);
        }
    __syncthreads();
    s_sort[tid] = v;
    int T = P * (P - 1) / 2;
    if (tid == 0) s_base = (T > 0) ? atomicAdd(&g_cursor, T) : 0;
    __syncthreads();             // publish s_sort and s_base
    int dbase = s_base;
    int carried = 0;
    for (int cb = 0; cb < T; cb += NB) {
        int t = cb + tid;
        int cnt = 0, jk = 0;
        float thr = 0.0f;
        if (t < T) {
            int a = 0;
            #pragma unroll
            for (int step = 128; step > 0; step >>= 1) {
                int na = a + step;
                if (na <= P - 2 && s_rowbase[na] <= t) a = na;
            }
            int b = a + 1 + (t - s_rowbase[a]);
            int jj = s_plist[a], kk = s_plist[b];
            thr = fmaxf(s_dd[jj], s_dd[kk]);
            jk  = jj | (kk << 8);
            cnt = ubcount(s_sort, thr);
        }
        int inc2 = block_scan_int(cnt, s_w4);
        int chunkTot = s_w4[0] + s_w4[1] + s_w4[2] + s_w4[3];
        if (t < T)
            g_trip[dbase + t] =
                make_int4(jk, __float_as_int(thr), carried + inc2 - cnt, i);
        carried += chunkTot;
    }
    if (tid == 0) g_atot[i] = carried;
}

__global__ __launch_bounds__(256) void k_abase() {
    __shared__ int s_w4[4];
    int tid = threadIdx.x;
    int v = g_atot[tid];
    int incl = block_scan_int(v, s_w4);
    g_abase[tid] = incl - v;     // exclusive prefix
}

// dense, load-balanced, barrier-free emission; 2-deep pipelined triplet loop.
__global__ __launch_bounds__(256) void k_write(int4* __restrict__ out, int maxQuads) {
    int tid = threadIdx.x;
    int wv = tid >> 6, ln = tid & 63;
    int W = (blockIdx.x << 2) | wv;            // 0..8191, flat wave id
    int Ttot = g_cursor;
    unsigned long long lanemask = (1ULL << ln) - 1ULL;
    int t = W;
    int4 tr = (t < Ttot) ? g_trip[t] : make_int4(0, 0, 0, 0);
    while (t < Ttot) {
        int tn = t + KW_WAVES;
        int4 nxt = (tn < Ttot) ? g_trip[tn] : make_int4(0, 0, 0, 0);
        int ai = tr.w;
        const float* row = g_ddneg + ai * NB;
        float v0 = row[ln], v1 = row[64 + ln];
        float v2 = row[128 + ln], v3 = row[192 + ln];
        int base = g_abase[ai] + tr.z;
        int jj = tr.x & 255, kk = tr.x >> 8;
        float thr = __int_as_float(tr.y);
        bool f0 = (v0 <= thr), f1 = (v1 <= thr);
        bool f2 = (v2 <= thr), f3 = (v3 <= thr);
        unsigned long long m0 = __ballot(f0), m1 = __ballot(f1);
        unsigned long long m2 = __ballot(f2), m3 = __ballot(f3);
        int b1 = base + __popcll(m0);
        int b2 = b1 + __popcll(m1);
        int b3 = b2 + __popcll(m2);
        if (f0) { int pos = base + __popcll(m0 & lanemask);
                  if (pos < maxQuads) out[pos] = make_int4(ai, jj, kk, ln); }
        if (f1) { int pos = b1 + __popcll(m1 & lanemask);
                  if (pos < maxQuads) out[pos] = make_int4(ai, jj, kk, 64 | ln); }
        if (f2) { int pos = b2 + __popcll(m2 & lanemask);
                  if (pos < maxQuads) out[pos] = make_int4(ai, jj, kk, 128 | ln); }
        if (f3) { int pos = b3 + __popcll(m3 & lanemask);
                  if (pos < maxQuads) out[pos] = make_int4(ai, jj, kk, 192 | ln); }
        tr = nxt;
        t = tn;
    }
}

extern "C" void kernel_launch(void* const* d_in, const int* in_sizes, int n_in,
                              void* d_out, int out_size, void* d_ws, size_t ws_size,
                              hipStream_t stream) {
    const float* logits = (const float*)d_in[0];
    const float* labels = (const float*)d_in[1];
    if (n_in >= 2 && in_sizes[0] == NB * NC && in_sizes[1] == NB * ND) {
        logits = (const float*)d_in[1];
        labels = (const float*)d_in[0];
    }
    int maxQuads = out_size / 4;

    k_prep <<<NB, NB, 0, stream>>>(logits, labels);
    k_count<<<NB, NB, 0, stream>>>();
    k_abase<<<1,  NB, 0, stream>>>();
    k_write<<<NB * NSPLIT, NB, 0, stream>>>((int4*)d_out, maxQuads);
}